// Round 2
// baseline (1661.852 us; speedup 1.0000x reference)
//
#include <hip/hip_runtime.h>
#include <stdint.h>

#define Hh   51
#define G4   204      // 4*H
#define Bsz  1024
#define Tin  512
#define Ttot 576      // Tin + future(64)
#define GRP  256      // threads per block (1 batch element per block)

__device__ __forceinline__ float fast_sigmoid(float x) {
    return 1.0f / (1.0f + __expf(-x));
}
// tanh(x) = 2*sigmoid(2x) - 1

__global__ __launch_bounds__(GRP, 2)
void lstm_seq_kernel(const float* __restrict__ inp,    // [B, Tin] fp32
                     const float* __restrict__ Wih1,   // [204, 1]
                     const float* __restrict__ Whh1,   // [204, 51]
                     const float* __restrict__ bih1,   // [204]
                     const float* __restrict__ bhh1,   // [204]
                     const float* __restrict__ Wih2,   // [204, 51]
                     const float* __restrict__ Whh2,   // [204, 51]
                     const float* __restrict__ bih2,   // [204]
                     const float* __restrict__ bhh2,   // [204]
                     const float* __restrict__ Wl,     // [1, 51]
                     const float* __restrict__ blp,    // [1]
                     float* __restrict__ outp)         // [B, Ttot] fp32
{
    const int j = threadIdx.x;      // gate-row index (0..203 active)
    const int b = blockIdx.x;       // batch element

    // hcat: [0..50] = h1, [51..101] = h2 (contiguous: layer-2 dot is one
    // length-102 dot; L1's pair 25 touches hcat[51] with a zero pad weight).
    __shared__ float hcat[104];
    __shared__ float gates[G4];
    __shared__ float xnb;           // feedback for the future phase

    if (j < 104) hcat[j] = 0.f;

    // ---- weights into registers (fp32) ----
    float w1[52];    // Whh1 row j, padded so pair-25 hi weight is 0
    float w2[102];   // [Wih2 row j | Whh2 row j]
    float b1j = 0.f, b2j = 0.f, wih1j = 0.f;
    if (j < G4) {
#pragma unroll
        for (int k = 0; k < Hh; ++k) w1[k] = Whh1[j * Hh + k];
        w1[51] = 0.f;
#pragma unroll
        for (int k = 0; k < Hh; ++k) w2[k] = Wih2[j * Hh + k];
#pragma unroll
        for (int k = 0; k < Hh; ++k) w2[Hh + k] = Whh2[j * Hh + k];
        b1j   = bih1[j] + bhh1[j];
        b2j   = bih2[j] + bhh2[j];
        wih1j = Wih1[j];
    }
    const float wlj = (j < Hh) ? Wl[j] : 0.f;
    const float blv = blp[0];
    float c1 = 0.f, c2 = 0.f;

    float xpref = inp[b * Tin + 0];   // prefetched x for t=0
    const bool is_tanh_gate = (j >= 2 * Hh) && (j < 3 * Hh);

    __syncthreads();

    for (int t = 0; t < Ttot; ++t) {
        // input phase: prefetched register; future phase: fed-back output
        float x = (t < Tin) ? xpref : xnb;
        float xnxt = 0.f;
        if (t + 1 < Tin) xnxt = inp[b * Tin + t + 1];   // prefetch next step

        // ---- layer 1 gates: a = b1 + x*wih1 + Whh1[j,:] . h1 ----
        if (j < G4) {
            float acc0 = __builtin_fmaf(x, wih1j, b1j);
            float acc1 = 0.f;
#pragma unroll
            for (int p = 0; p < 26; ++p) {
                float2 hp = *(const float2*)&hcat[2 * p];
                acc0 = __builtin_fmaf(w1[2 * p],     hp.x, acc0);
                acc1 = __builtin_fmaf(w1[2 * p + 1], hp.y, acc1);
            }
            float a   = acc0 + acc1;
            float arg = is_tanh_gate ? 2.f * a : a;
            float s   = fast_sigmoid(arg);
            gates[j] = is_tanh_gate ? (2.f * s - 1.f) : s;
        }
        __syncthreads();

        // ---- layer 1 state ----
        if (j < Hh) {
            float gi = gates[j],           gf = gates[Hh + j];
            float gg = gates[2 * Hh + j],  go = gates[3 * Hh + j];
            c1 = __builtin_fmaf(gf, c1, gi * gg);
            float th = 2.f * fast_sigmoid(2.f * c1) - 1.f;
            hcat[j] = go * th;
        }
        __syncthreads();

        // ---- layer 2 gates: a = b2 + [Wih2|Whh2][j,:] . [h1;h2] ----
        if (j < G4) {
            float acc0 = b2j, acc1 = 0.f;
#pragma unroll
            for (int p = 0; p < 51; ++p) {
                float2 hp = *(const float2*)&hcat[2 * p];
                acc0 = __builtin_fmaf(w2[2 * p],     hp.x, acc0);
                acc1 = __builtin_fmaf(w2[2 * p + 1], hp.y, acc1);
            }
            float a   = acc0 + acc1;
            float arg = is_tanh_gate ? 2.f * a : a;
            float s   = fast_sigmoid(arg);
            gates[j] = is_tanh_gate ? (2.f * s - 1.f) : s;
        }
        __syncthreads();

        // ---- layer 2 state + linear output (wave-0 shuffle reduce) ----
        float contrib = 0.f;
        if (j < Hh) {
            float gi = gates[j],           gf = gates[Hh + j];
            float gg = gates[2 * Hh + j],  go = gates[3 * Hh + j];
            c2 = __builtin_fmaf(gf, c2, gi * gg);
            float th = 2.f * fast_sigmoid(2.f * c2) - 1.f;
            float h2 = go * th;
            hcat[Hh + j] = h2;
            contrib = wlj * h2;
        }
        if (j < 64) {                      // first wave only
            float s = contrib;
#pragma unroll
            for (int m = 32; m >= 1; m >>= 1) s += __shfl_xor(s, m, 64);
            if (j == 0) {
                float ov = s + blv;
                xnb = ov;                  // feedback for future phase
                outp[(size_t)b * Ttot + t] = ov;
            }
        }
        __syncthreads();
        xpref = xnxt;
    }
}

extern "C" void kernel_launch(void* const* d_in, const int* in_sizes, int n_in,
                              void* d_out, int out_size, void* d_ws, size_t ws_size,
                              hipStream_t stream) {
    (void)in_sizes; (void)n_in; (void)out_size; (void)d_ws; (void)ws_size;
    lstm_seq_kernel<<<dim3(Bsz), dim3(GRP), 0, stream>>>(
        (const float*)d_in[0], (const float*)d_in[1],
        (const float*)d_in[2], (const float*)d_in[3],
        (const float*)d_in[4], (const float*)d_in[5],
        (const float*)d_in[6], (const float*)d_in[7],
        (const float*)d_in[8], (const float*)d_in[9],
        (const float*)d_in[10], (float*)d_out);
}